// Round 1
// 260.104 us; speedup vs baseline: 1.0664x; 1.0664x over previous
//
#include <hip/hip_runtime.h>
#include <stdint.h>

#define NCLS 172
#define IGN 255
#define HW 65536          // 256*256
#define NPIX 262144       // 4*256*256
#define EPSV 1e-7f
#define TP 64             // pixels per LDS tile
#define NTILE 4           // tiles per block (256 px/block)
#define PIXPERBLK (TP * NTILE)
#define NSTAGE 16         // staged global partial buffers
#define SS 520            // per stage: [0,172) inter | [172,344) cnt | [344,516) union | 516 ce | 517 nvalid

__device__ __forceinline__ float waveReduceSum(float v) {
    #pragma unroll
    for (int off = 32; off > 0; off >>= 1) v += __shfl_down(v, off, 64);
    return v;
}

// async global->LDS, 16B per lane; LDS dest = wave-uniform base + lane*16 (linear)
__device__ __forceinline__ void gl_lds16(const float* g, float* l) {
    __builtin_amdgcn_global_load_lds(
        (const __attribute__((address_space(1))) void*)g,
        (__attribute__((address_space(3))) void*)l, 16, 0, 0);
}

// Single fused pass: pred is read from HBM exactly once.
// Per block: 4 sequential 64px x 172cls LDS tiles. Per tile:
//   stage (43 x global_load_lds_dwordx4) -> barrier
//   phase1: per-pixel sumexp (wave q owns classes [q*43, q*43+43)), invs/CE/inter
//   phase2: per-class union partial, diagonal LDS walk (conflict-free on linear tile)
__global__ __launch_bounds__(256) void seg_fused(
    const float* __restrict__ pred, const int* __restrict__ tgt,
    float* __restrict__ part)
{
    __shared__ float tile[NCLS * TP];      // 44032 B, MUST stay linear (global_load_lds dest)
    __shared__ float sPart[256];
    __shared__ float sInvs[TP];
    __shared__ float sInter[NCLS];
    __shared__ unsigned int sCnt[NCLS];

    const int tid  = threadIdx.x;
    const int lane = tid & 63;
    const int wv   = tid >> 6;
    const int p    = lane;                 // pixel index for phase 1
    const int q    = wv;                   // class chunk for phase 1 (172 = 4*43)

    for (int i = tid; i < NCLS; i += 256) { sInter[i] = 0.f; sCnt[i] = 0u; }

    const int pix0 = blockIdx.x * PIXPERBLK;
    const int b    = pix0 >> 16;
    const int hw0  = pix0 & (HW - 1);
    const float* gb = pred + (size_t)b * NCLS * HW + hw0;

    // staging lane decomposition: 64 lanes x 16B = 4 class rows (256B each) per instr
    const int lc = lane >> 4;              // class sub-row 0..3
    const int lp = (lane & 15) << 2;       // pixel float offset 0..60

    float unionAcc = 0.f;                  // thread t<NCLS: union partial for class t
    float ceAcc = 0.f, nvAcc = 0.f;        // live on tid==0 only

    for (int tI = 0; tI < NTILE; ++tI) {
        const float* gt = gb + tI * TP;
        // ---- stage tile: 43 instrs, wave wv covers class rows {wv*4 + 16k} ----
        for (int cb = wv * 4; cb < NCLS; cb += 16)
            gl_lds16(gt + (size_t)(cb + lc) * HW + lp, &tile[cb * TP]);
        __syncthreads();                   // drains vmcnt before barrier

        // ---- phase 1: per-pixel sum of exp over this wave's 43 classes ----
        const int c0 = q * 43;
        float s0 = 0.f, s1 = 0.f;
        #pragma unroll
        for (int i = 0; i < 42; i += 2) {
            s0 += __expf(tile[(c0 + i    ) * TP + p]);
            s1 += __expf(tile[(c0 + i + 1) * TP + p]);
        }
        s0 += __expf(tile[(c0 + 42) * TP + p]);
        sPart[tid] = s0 + s1;
        __syncthreads();

        if (tid < 64) {                    // wave 0 finalizes each pixel
            const float s    = (sPart[p] + sPart[64 + p]) + (sPart[128 + p] + sPart[192 + p]);
            const float invs = 1.0f / s;
            sInvs[p] = invs;
            const int  t     = tgt[pix0 + tI * TP + p];
            const bool valid = (t != IGN);
            const int  st    = valid ? t : 0;
            const float xt   = tile[st * TP + p];   // banks p%32: conflict-free gather
            const float nll  = valid ? (__logf(s) - xt) : 0.f;
            if (valid) {
                atomicAdd(&sInter[st], __expf(xt) * invs);
                atomicAdd(&sCnt[st], 1u);
            }
            const float vr = waveReduceSum(nll);
            const float nr = waveReduceSum(valid ? 1.f : 0.f);
            if (lane == 0) { ceAcc += vr; nvAcc += nr; }
        }
        __syncthreads();

        // ---- phase 2: per-class union, diagonal walk keeps banks spread ----
        if (tid < NCLS) {
            const int c = tid;
            float u0 = 0.f, u1 = 0.f;
            #pragma unroll 4
            for (int k = 0; k < TP; k += 2) {
                const int p0 = (c + k    ) & (TP - 1);
                const int p1 = (c + k + 1) & (TP - 1);
                u0 += __expf(tile[c * TP + p0]) * sInvs[p0];
                u1 += __expf(tile[c * TP + p1]) * sInvs[p1];
            }
            unionAcc += u0 + u1;
        }
        __syncthreads();                   // tile reuse guard for next stage
    }

    // ---- flush per-block partials to 16-way staged global buffers ----
    float* pb = part + (size_t)(blockIdx.x & (NSTAGE - 1)) * SS;
    for (int i = tid; i < NCLS; i += 256) {
        const float vi = sInter[i];
        if (vi != 0.f) atomicAdd(&pb[i], vi);
        const unsigned int ci = sCnt[i];
        if (ci != 0u) atomicAdd(&pb[NCLS + i], (float)ci);
    }
    if (tid < NCLS) atomicAdd(&pb[344 + tid], unionAcc);
    if (tid == 0) { atomicAdd(&pb[516], ceAcc); atomicAdd(&pb[517], nvAcc); }
}

__global__ __launch_bounds__(256) void seg_fin(
    const float* __restrict__ part, float* __restrict__ out)
{
    __shared__ float sT[256], sN[256];
    const int tid = threadIdx.x;
    float term = 0.f, nv = 0.f;
    if (tid < NCLS) {
        float inter = 0.f, cnt = 0.f, uni = 0.f;
        #pragma unroll
        for (int st = 0; st < NSTAGE; ++st) {
            inter += part[st * SS + tid];
            cnt   += part[st * SS + NCLS + tid];
            uni   += part[st * SS + 344 + tid];
        }
        const float u = uni + cnt;
        if (u > 0.f) { term = (2.f * inter + EPSV) / (u + EPSV); nv = 1.f; }
    }
    sT[tid] = term; sN[tid] = nv;
    __syncthreads();
    #pragma unroll
    for (int s2 = 128; s2 > 0; s2 >>= 1) {
        if (tid < s2) { sT[tid] += sT[tid + s2]; sN[tid] += sN[tid + s2]; }
        __syncthreads();
    }
    if (tid == 0) {
        float ce = 0.f, nvl = 0.f;
        #pragma unroll
        for (int st = 0; st < NSTAGE; ++st) {
            ce  += part[st * SS + 516];
            nvl += part[st * SS + 517];
        }
        const float ceo  = ce / fmaxf(nvl, 1.f);
        const float dice = (sN[0] > 0.f) ? (1.f - sT[0] / fmaxf(sN[0], 1.f)) : 0.f;
        out[0] = ceo + 0.5f * dice;
    }
}

extern "C" void kernel_launch(void* const* d_in, const int* in_sizes, int n_in,
                              void* d_out, int out_size, void* d_ws, size_t ws_size,
                              hipStream_t stream) {
    const float* pred = (const float*)d_in[0];
    const int*   tgt  = (const int*)d_in[1];
    float* out  = (float*)d_out;
    float* part = (float*)d_ws;

    hipMemsetAsync(d_ws, 0, NSTAGE * SS * sizeof(float), stream);
    seg_fused<<<NPIX / PIXPERBLK, 256, 0, stream>>>(pred, tgt, part);
    seg_fin<<<1, 256, 0, stream>>>(part, out);
}

// Round 2
// 255.323 us; speedup vs baseline: 1.0864x; 1.0187x over previous
//
#include <hip/hip_runtime.h>
#include <stdint.h>

#define NCLS 172
#define IGN 255
#define HW 65536          // 256*256
#define NPIX 262144       // 4*256*256
#define EPSV 1e-7f
#define TP 32             // pixels per LDS tile
#define TROWS 176         // padded class rows (172 + 4 pad, DMA target safety)
#define NTILE 4           // tiles per block -> 128 px/block
#define PIXPERBLK (TP * NTILE)
#define NSTAGE 32         // staged global partial buffers
#define SS 520            // per stage: [0,172) inter | [172,344) cnt | [344,516) union | 516 ce | 517 nvalid

__device__ __forceinline__ void gl_lds16(const float* g, float* l) {
    __builtin_amdgcn_global_load_lds(
        (const __attribute__((address_space(1))) void*)g,
        (__attribute__((address_space(3))) void*)l, 16, 0, 0);
}

// Fused single-read kernel. Per block: 4 sequential 32px x 172cls LDS tiles.
// Per tile: stage (22 x global_load_lds_dwordx4) -> phase1 per-pixel sumexp with
// exp written back into the tile -> finalize (invs/CE/inter, 32 threads) ->
// phase2 per-class union (pure LDS fma, diagonal walk). 25 KB LDS -> 6 blocks/CU.
__global__ __launch_bounds__(256) void seg_fused(
    const float* __restrict__ pred, const int* __restrict__ tgt,
    float* __restrict__ part)
{
    __shared__ float tile[TROWS * TP];     // 22528 B, linear (global_load_lds dest)
    __shared__ float sPart[128];           // 4 waves x 32 px chunk-pair partials
    __shared__ float sInvs[TP];
    __shared__ float sInter[NCLS];
    __shared__ unsigned int sCnt[NCLS];

    const int tid   = threadIdx.x;
    const int lane  = tid & 63;
    const int wv    = tid >> 6;
    const int p     = tid & 31;            // pixel within tile
    const int chunk = tid >> 5;            // class chunk 0..7 (c = chunk + 8k)

    for (int i = tid; i < NCLS; i += 256) { sInter[i] = 0.f; sCnt[i] = 0u; }

    const int pix0 = blockIdx.x * PIXPERBLK;
    const int b    = pix0 >> 16;
    const int hw0  = pix0 & (HW - 1);
    const float* gb = pred + (size_t)b * NCLS * HW + hw0;

    // staging lane decomposition: 64 lanes x 16B = 8 class rows (128B each)
    const int scb = lane >> 3;             // class sub-row 0..7
    const int spo = (lane & 7) << 2;       // pixel float offset 0..28

    float unionAcc = 0.f;                  // thread t<NCLS: union partial for class t
    float ceAcc = 0.f, nvAcc = 0.f;        // live on tid==0

    for (int tI = 0; tI < NTILE; ++tI) {
        const float* gt = gb + tI * TP;

        // ---- stage: 22 instrs; rows 172..175 clamp to 171 (land in LDS pad) ----
        for (int ib = wv; ib < 22; ib += 4) {
            int cb = ib * 8 + scb;
            if (cb > NCLS - 1) cb = NCLS - 1;
            gl_lds16(gt + (size_t)cb * HW + spo, &tile[ib * (8 * TP)]);
        }
        __syncthreads();

        // ---- phase 1: sumexp over this chunk's classes, exp written back ----
        float s0 = 0.f, s1 = 0.f;
        #pragma unroll
        for (int k = 0; k < 20; k += 2) {
            const int i0 = (chunk + 8 * k) * TP + p;
            const int i1 = (chunk + 8 * k + 8) * TP + p;
            const float e0 = __expf(tile[i0]);
            const float e1 = __expf(tile[i1]);
            tile[i0] = e0; tile[i1] = e1;
            s0 += e0; s1 += e1;
        }
        {   const int i0 = (chunk + 160) * TP + p;
            const float e = __expf(tile[i0]); tile[i0] = e; s0 += e; }
        if (chunk < 4) {                   // classes 168..171 (uniform per wave)
            const int i1 = (chunk + 168) * TP + p;
            const float e = __expf(tile[i1]); tile[i1] = e; s1 += e;
        }
        float sv = s0 + s1;
        sv += __shfl_down(sv, 32, 64);     // combine the wave's two chunks
        if (lane < 32) sPart[wv * 32 + p] = sv;
        __syncthreads();

        // ---- finalize: invs, CE, inter/cnt (32 threads) ----
        if (tid < 32) {
            const float s    = (sPart[p] + sPart[32 + p]) + (sPart[64 + p] + sPart[96 + p]);
            const float invs = 1.0f / s;
            sInvs[p] = invs;
            const int  t     = tgt[pix0 + tI * TP + p];
            const bool valid = (t != IGN);
            const int  st    = valid ? t : 0;
            const float et   = tile[st * TP + p];   // exp(x_t), banks p: conflict-free
            const float pt   = et * invs;
            float nll = valid ? -__logf(pt) : 0.f;
            float nv  = valid ? 1.f : 0.f;
            if (valid) { atomicAdd(&sInter[st], pt); atomicAdd(&sCnt[st], 1u); }
            #pragma unroll
            for (int off = 16; off > 0; off >>= 1) {
                nll += __shfl_down(nll, off, 64);
                nv  += __shfl_down(nv,  off, 64);
            }
            if (tid == 0) { ceAcc += nll; nvAcc += nv; }
        }
        __syncthreads();

        // ---- phase 2: per-class union, pure fma on cached exp, diagonal walk ----
        if (tid < NCLS) {
            const float* tr = &tile[tid * TP];
            float u0 = 0.f, u1 = 0.f;
            #pragma unroll
            for (int k = 0; k < TP; k += 2) {
                const int p0 = (tid + k)     & (TP - 1);
                const int p1 = (tid + k + 1) & (TP - 1);
                u0 += tr[p0] * sInvs[p0];
                u1 += tr[p1] * sInvs[p1];
            }
            unionAcc += u0 + u1;
        }
        __syncthreads();                   // tile reuse guard for next stage
    }

    // ---- flush per-block partials to staged global buffers ----
    float* pb = part + (size_t)(blockIdx.x & (NSTAGE - 1)) * SS;
    for (int i = tid; i < NCLS; i += 256) {
        const float vi = sInter[i];
        if (vi != 0.f) atomicAdd(&pb[i], vi);
        const unsigned int ci = sCnt[i];
        if (ci != 0u) atomicAdd(&pb[NCLS + i], (float)ci);
    }
    if (tid < NCLS) atomicAdd(&pb[344 + tid], unionAcc);
    if (tid == 0) { atomicAdd(&pb[516], ceAcc); atomicAdd(&pb[517], nvAcc); }
}

__global__ __launch_bounds__(256) void seg_fin(
    const float* __restrict__ part, float* __restrict__ out)
{
    __shared__ float sT[256], sN[256];
    const int tid = threadIdx.x;
    float term = 0.f, nv = 0.f;
    if (tid < NCLS) {
        float inter = 0.f, cnt = 0.f, uni = 0.f;
        for (int st = 0; st < NSTAGE; ++st) {
            inter += part[st * SS + tid];
            cnt   += part[st * SS + NCLS + tid];
            uni   += part[st * SS + 344 + tid];
        }
        const float u = uni + cnt;
        if (u > 0.f) { term = (2.f * inter + EPSV) / (u + EPSV); nv = 1.f; }
    }
    sT[tid] = term; sN[tid] = nv;
    __syncthreads();
    #pragma unroll
    for (int s2 = 128; s2 > 0; s2 >>= 1) {
        if (tid < s2) { sT[tid] += sT[tid + s2]; sN[tid] += sN[tid + s2]; }
        __syncthreads();
    }
    if (tid == 0) {
        float ce = 0.f, nvl = 0.f;
        for (int st = 0; st < NSTAGE; ++st) {
            ce  += part[st * SS + 516];
            nvl += part[st * SS + 517];
        }
        const float ceo  = ce / fmaxf(nvl, 1.f);
        const float dice = (sN[0] > 0.f) ? (1.f - sT[0] / fmaxf(sN[0], 1.f)) : 0.f;
        out[0] = ceo + 0.5f * dice;
    }
}

extern "C" void kernel_launch(void* const* d_in, const int* in_sizes, int n_in,
                              void* d_out, int out_size, void* d_ws, size_t ws_size,
                              hipStream_t stream) {
    const float* pred = (const float*)d_in[0];
    const int*   tgt  = (const int*)d_in[1];
    float* out  = (float*)d_out;
    float* part = (float*)d_ws;

    hipMemsetAsync(d_ws, 0, NSTAGE * SS * sizeof(float), stream);
    seg_fused<<<NPIX / PIXPERBLK, 256, 0, stream>>>(pred, tgt, part);
    seg_fin<<<1, 256, 0, stream>>>(part, out);
}